// Round 12
// baseline (114.007 us; speedup 1.0000x reference)
//
#include <hip/hip_runtime.h>
#include <hip/hip_fp16.h>

#define B1 256
#define IT1 8                 // pairs per thread
#define CH1 (B1 * IT1)        // 2048 — shared tiling for all kernels
#define B2 1024
#define VMAX 2.2f

typedef float f32x4 __attribute__((ext_vector_type(4)));
typedef unsigned u32x4 __attribute__((ext_vector_type(4)));

struct DSum { double x, y; };

__device__ __forceinline__ float fast_tanh(float x) {
  float e = __expf(2.0f * x);
  return 1.0f - 2.0f / (e + 1.0f);
}

__device__ __forceinline__ float fast_atan2(float y, float x) {
  float ax = fabsf(x), ay = fabsf(y);
  float mn = fminf(ax, ay), mx = fmaxf(ax, ay);
  float a = mn / (mx + 1e-30f);
  float s = a * a;
  float r = ((-0.0464964749f * s + 0.15931422f) * s - 0.327622764f) * s * a + a;
  if (ay > ax) r = 1.57079637f - r;
  if (x < 0.0f) r = 3.14159274f - r;
  return copysignf(r, y);
}

__device__ __forceinline__ unsigned packh2(float x, float y) {
  __half2 h = __floats2half2_rn(x, y);
  return *(unsigned*)&h;
}
__device__ __forceinline__ float2 unpackh2(unsigned u) {
  __half2 h = *(__half2*)&u;
  return __half22float2(h);
}

// ---------- Path 1 (fp16 intermediate) ----------
// Kernel A: read U once, uv=tanh*vmax -> fp16 pairs to ws + block sums (of the
// ROUNDED values, x dt, fp64) so prefix offsets are exactly consistent.
__global__ __launch_bounds__(B1) void wi_prep(
    const float* __restrict__ U, const float* __restrict__ dtp,
    unsigned* __restrict__ uvh, DSum* __restrict__ bsum, int N)
{
  const int t = threadIdx.x;
  const int lane = t & 63, wid = t >> 6;
  const long base = (long)blockIdx.x * CH1 + (long)t * IT1;
  float sx = 0.f, sy = 0.f;
  if (base + IT1 <= (long)N) {
    const f32x4* p = (const f32x4*)(U + 2 * base);
    unsigned pk[IT1];
    #pragma unroll
    for (int i = 0; i < IT1 / 2; ++i) {
      f32x4 a = p[i];
      unsigned q0 = packh2(fast_tanh(a.x) * VMAX, fast_tanh(a.y) * VMAX);
      unsigned q1 = packh2(fast_tanh(a.z) * VMAX, fast_tanh(a.w) * VMAX);
      pk[2*i] = q0; pk[2*i+1] = q1;
      float2 r0 = unpackh2(q0), r1 = unpackh2(q1);
      sx += r0.x + r1.x; sy += r0.y + r1.y;
    }
    u32x4 v0 = { pk[0], pk[1], pk[2], pk[3] };
    u32x4 v1 = { pk[4], pk[5], pk[6], pk[7] };
    *(u32x4*)(uvh + base) = v0;
    *(u32x4*)(uvh + base + 4) = v1;
  } else {
    for (int i = 0; i < IT1; ++i) {
      long idx = base + i;
      if (idx < N) {
        unsigned q = packh2(fast_tanh(U[2*idx]) * VMAX, fast_tanh(U[2*idx+1]) * VMAX);
        uvh[idx] = q;
        float2 r = unpackh2(q);
        sx += r.x; sy += r.y;
      }
    }
  }
  #pragma unroll
  for (int o = 1; o < 64; o <<= 1) { sx += __shfl_xor(sx, o); sy += __shfl_xor(sy, o); }
  __shared__ double wsx[B1/64], wsy[B1/64];
  if (lane == 0) { wsx[wid] = (double)sx; wsy[wid] = (double)sy; }
  __syncthreads();
  if (t == 0) {
    const double dtd = (double)(*dtp);
    double ax = 0.0, ay = 0.0;
    #pragma unroll
    for (int w = 0; w < B1/64; ++w) { ax += wsx[w]; ay += wsy[w]; }
    bsum[blockIdx.x].x = ax * dtd;
    bsum[blockIdx.x].y = ay * dtd;
  }
}

// Kernel B: single-block fp64 exclusive scan, wave-shuffle based.
__global__ __launch_bounds__(B2) void wi_scan_blocks(DSum* bsum, int nblocks)
{
  const int t = threadIdx.x;
  const int lane = t & 63, wid = t >> 6;
  const int per = (nblocks + B2 - 1) / B2;
  const int s = t * per;
  const int e = min(s + per, nblocks);
  double tx = 0.0, ty = 0.0;
  for (int i = s; i < e; ++i) { tx += bsum[i].x; ty += bsum[i].y; }
  double ix = tx, iy = ty;
  #pragma unroll
  for (int o = 1; o < 64; o <<= 1) {
    double ux = __shfl_up(ix, o), uy = __shfl_up(iy, o);
    if (lane >= o) { ix += ux; iy += uy; }
  }
  __shared__ double wx[B2/64], wy[B2/64];
  if (lane == 63) { wx[wid] = ix; wy[wid] = iy; }
  __syncthreads();
  double wbx = 0.0, wby = 0.0;
  #pragma unroll
  for (int w = 0; w < B2/64; ++w) {
    if (w < wid) { wbx += wx[w]; wby += wy[w]; }
  }
  double rx = wbx + ix - tx;
  double ry = wby + iy - ty;
  for (int i = s; i < e; ++i) {
    double vx = bsum[i].x, vy = bsum[i].y;
    bsum[i].x = rx; bsum[i].y = ry;
    rx += vx; ry += vy;
  }
}

// Kernel C: read fp16 uv (L3-hot), scan, stage in LDS, dense nt stores.
__global__ __launch_bounds__(B1) void wi_emit_h(
    const unsigned* __restrict__ uvh, const float* __restrict__ x0,
    const float* __restrict__ dtp, const DSum* __restrict__ boff,
    float* __restrict__ out, int N)
{
  __shared__ f32x4 stage[CH1];        // 32 KiB
  __shared__ float wsum_x[B1/64], wsum_y[B1/64];

  const int t = threadIdx.x;
  const int lane = t & 63, wid = t >> 6;
  const long base = (long)blockIdx.x * CH1 + (long)t * IT1;
  const float dt = *dtp;

  float vx[IT1], vy[IT1];
  const bool full = (base + IT1 <= (long)N);
  if (full) {
    u32x4 v0 = *(const u32x4*)(uvh + base);
    u32x4 v1 = *(const u32x4*)(uvh + base + 4);
    unsigned pk[IT1] = { v0.x, v0.y, v0.z, v0.w, v1.x, v1.y, v1.z, v1.w };
    #pragma unroll
    for (int i = 0; i < IT1; ++i) {
      float2 r = unpackh2(pk[i]);
      vx[i] = r.x; vy[i] = r.y;
    }
  } else {
    for (int i = 0; i < IT1; ++i) {
      long idx = base + i;
      if (idx < N) { float2 r = unpackh2(uvh[idx]); vx[i] = r.x; vy[i] = r.y; }
      else { vx[i] = 0.f; vy[i] = 0.f; }
    }
  }

  float px[IT1], py[IT1];
  float sx = 0.f, sy = 0.f;
  #pragma unroll
  for (int i = 0; i < IT1; ++i) { sx += vx[i]*dt; px[i] = sx; sy += vy[i]*dt; py[i] = sy; }
  const float totx = sx, toty = sy;

  #pragma unroll
  for (int o = 1; o < 64; o <<= 1) {
    float ux = __shfl_up(sx, o), uy = __shfl_up(sy, o);
    if (lane >= o) { sx += ux; sy += uy; }
  }
  if (lane == 63) { wsum_x[wid] = sx; wsum_y[wid] = sy; }
  __syncthreads();
  float wbx = 0.f, wby = 0.f;
  #pragma unroll
  for (int w = 0; w < B1/64; ++w) {
    if (w < wid) { wbx += wsum_x[w]; wby += wsum_y[w]; }
  }
  const float exb = wbx + sx - totx;
  const float eyb = wby + sy - toty;

  const double ox = boff[blockIdx.x].x + (double)x0[0];
  const double oy = boff[blockIdx.x].y + (double)x0[1];

  #pragma unroll
  for (int i = 0; i < IT1; ++i) {
    float posx = (float)(ox + (double)(exb + px[i]));
    float posy = (float)(oy + (double)(eyb + py[i]));
    float th = fast_atan2(vy[i], vx[i] + 1e-9f);
    float vv = fminf(sqrtf(vx[i]*vx[i] + vy[i]*vy[i] + 1e-12f), VMAX);
    f32x4 r; r.x = posx; r.y = posy; r.z = th; r.w = vv;
    const int k = t * IT1 + i;
    stage[k ^ ((k >> 3) & 7)] = r;
  }
  __syncthreads();

  const long tile0 = (long)blockIdx.x * CH1;
  f32x4* o4 = (f32x4*)out;
  #pragma unroll
  for (int i = 0; i < IT1; ++i) {
    const int k = i * B1 + t;
    const long g = tile0 + k;
    if (g < (long)N) __builtin_nontemporal_store(stage[k ^ ((k >> 3) & 7)], o4 + 1 + g);
  }
  if (blockIdx.x == 0 && t == 0) {
    f32x4 r; r.x = x0[0]; r.y = x0[1]; r.z = x0[2]; r.w = x0[3];
    o4[0] = r;
  }
}

// ---------- Path 2 fallback (R7, no intermediate) ----------
__global__ __launch_bounds__(B1) void wi_partial(
    const float* __restrict__ U, const float* __restrict__ dtp,
    DSum* __restrict__ bsum, int N)
{
  const int t = threadIdx.x;
  const int lane = t & 63, wid = t >> 6;
  const long base = (long)blockIdx.x * CH1 + (long)t * IT1;
  float sx = 0.f, sy = 0.f;
  if (base + IT1 <= (long)N) {
    const f32x4* p = (const f32x4*)(U + 2 * base);
    #pragma unroll
    for (int i = 0; i < IT1 / 2; ++i) {
      f32x4 a = p[i];
      sx += fast_tanh(a.x) + fast_tanh(a.z);
      sy += fast_tanh(a.y) + fast_tanh(a.w);
    }
  } else {
    for (int i = 0; i < IT1; ++i) {
      long idx = base + i;
      if (idx < N) { sx += fast_tanh(U[2*idx]); sy += fast_tanh(U[2*idx+1]); }
    }
  }
  #pragma unroll
  for (int o = 1; o < 64; o <<= 1) { sx += __shfl_xor(sx, o); sy += __shfl_xor(sy, o); }
  __shared__ double wsx[B1/64], wsy[B1/64];
  if (lane == 0) { wsx[wid] = (double)sx; wsy[wid] = (double)sy; }
  __syncthreads();
  if (t == 0) {
    const float sc = VMAX * (*dtp);
    double ax = 0.0, ay = 0.0;
    #pragma unroll
    for (int w = 0; w < B1/64; ++w) { ax += wsx[w]; ay += wsy[w]; }
    bsum[blockIdx.x].x = ax * (double)sc;
    bsum[blockIdx.x].y = ay * (double)sc;
  }
}

__global__ __launch_bounds__(B1) void wi_emit(
    const float* __restrict__ U, const float* __restrict__ x0,
    const float* __restrict__ dtp, const DSum* __restrict__ boff,
    float* __restrict__ out, int N)
{
  __shared__ f32x4 stage[CH1];
  __shared__ float wsum_x[B1/64], wsum_y[B1/64];
  const int t = threadIdx.x;
  const int lane = t & 63, wid = t >> 6;
  const long base = (long)blockIdx.x * CH1 + (long)t * IT1;
  const float dt = *dtp;
  float vx[IT1], vy[IT1];
  const bool full = (base + IT1 <= (long)N);
  if (full) {
    const f32x4* p = (const f32x4*)(U + 2 * base);
    #pragma unroll
    for (int i = 0; i < IT1 / 2; ++i) {
      f32x4 a = p[i];
      vx[2*i]   = fast_tanh(a.x) * VMAX; vy[2*i]   = fast_tanh(a.y) * VMAX;
      vx[2*i+1] = fast_tanh(a.z) * VMAX; vy[2*i+1] = fast_tanh(a.w) * VMAX;
    }
  } else {
    for (int i = 0; i < IT1; ++i) {
      long idx = base + i;
      if (idx < N) { vx[i] = fast_tanh(U[2*idx]) * VMAX; vy[i] = fast_tanh(U[2*idx+1]) * VMAX; }
      else { vx[i] = 0.f; vy[i] = 0.f; }
    }
  }
  float px[IT1], py[IT1];
  float sx = 0.f, sy = 0.f;
  #pragma unroll
  for (int i = 0; i < IT1; ++i) { sx += vx[i]*dt; px[i] = sx; sy += vy[i]*dt; py[i] = sy; }
  const float totx = sx, toty = sy;
  #pragma unroll
  for (int o = 1; o < 64; o <<= 1) {
    float ux = __shfl_up(sx, o), uy = __shfl_up(sy, o);
    if (lane >= o) { sx += ux; sy += uy; }
  }
  if (lane == 63) { wsum_x[wid] = sx; wsum_y[wid] = sy; }
  __syncthreads();
  float wbx = 0.f, wby = 0.f;
  #pragma unroll
  for (int w = 0; w < B1/64; ++w) {
    if (w < wid) { wbx += wsum_x[w]; wby += wsum_y[w]; }
  }
  const float exb = wbx + sx - totx;
  const float eyb = wby + sy - toty;
  const double ox = boff[blockIdx.x].x + (double)x0[0];
  const double oy = boff[blockIdx.x].y + (double)x0[1];
  #pragma unroll
  for (int i = 0; i < IT1; ++i) {
    float posx = (float)(ox + (double)(exb + px[i]));
    float posy = (float)(oy + (double)(eyb + py[i]));
    float th = fast_atan2(vy[i], vx[i] + 1e-9f);
    float vv = fminf(sqrtf(vx[i]*vx[i] + vy[i]*vy[i] + 1e-12f), VMAX);
    f32x4 r; r.x = posx; r.y = posy; r.z = th; r.w = vv;
    const int k = t * IT1 + i;
    stage[k ^ ((k >> 3) & 7)] = r;
  }
  __syncthreads();
  const long tile0 = (long)blockIdx.x * CH1;
  f32x4* o4 = (f32x4*)out;
  #pragma unroll
  for (int i = 0; i < IT1; ++i) {
    const int k = i * B1 + t;
    const long g = tile0 + k;
    if (g < (long)N) __builtin_nontemporal_store(stage[k ^ ((k >> 3) & 7)], o4 + 1 + g);
  }
  if (blockIdx.x == 0 && t == 0) {
    f32x4 r; r.x = x0[0]; r.y = x0[1]; r.z = x0[2]; r.w = x0[3];
    o4[0] = r;
  }
}

extern "C" void kernel_launch(void* const* d_in, const int* in_sizes, int n_in,
                              void* d_out, int out_size, void* d_ws, size_t ws_size,
                              hipStream_t stream) {
  const float* x0 = (const float*)d_in[0];
  const float* U  = (const float*)d_in[1];
  const float* dt = (const float*)d_in[2];
  float* out = (float*)d_out;
  const int N = in_sizes[1] / 2;
  const int nb = (N + CH1 - 1) / CH1;    // 8192

  const size_t uvh_bytes = ((size_t)N * 4 + 255) & ~(size_t)255;
  const size_t needed = uvh_bytes + (size_t)nb * sizeof(DSum);

  if (ws_size >= needed) {
    unsigned* uvh = (unsigned*)d_ws;
    DSum* bsum = (DSum*)((char*)d_ws + uvh_bytes);
    wi_prep<<<nb, B1, 0, stream>>>(U, dt, uvh, bsum, N);
    wi_scan_blocks<<<1, B2, 0, stream>>>(bsum, nb);
    wi_emit_h<<<nb, B1, 0, stream>>>(uvh, x0, dt, bsum, out, N);
  } else {
    DSum* bsum = (DSum*)d_ws;
    wi_partial<<<nb, B1, 0, stream>>>(U, dt, bsum, N);
    wi_scan_blocks<<<1, B2, 0, stream>>>(bsum, nb);
    wi_emit<<<nb, B1, 0, stream>>>(U, x0, dt, bsum, out, N);
  }
}

// Round 13
// 108.349 us; speedup vs baseline: 1.0522x; 1.0522x over previous
//
#include <hip/hip_runtime.h>
#include <hip/hip_fp16.h>
#include <hip/hip_cooperative_groups.h>

#define NB 1024               // target co-resident blocks: 256 CU x 4 blocks/CU
#define BT 256
#define SECS 8
#define PPS 8                 // pairs per thread per section
#define PPT (SECS * PPS)      // 64 pairs per thread
#define SEC_PAIRS (BT * PPS)  // 2048 pairs per section
#define SPAN (BT * PPT)       // 16384 pairs per block; NB*SPAN = 2^24 = H
#define B1 256
#define IT1 8
#define CH1 (B1 * IT1)        // 2048
#define B2 1024
#define VMAX 2.2f

typedef float f32x4 __attribute__((ext_vector_type(4)));
struct DSum { double x, y; };

__device__ __forceinline__ float fast_tanh(float x) {
  float e = __expf(2.0f * x);
  return 1.0f - 2.0f / (e + 1.0f);
}

__device__ __forceinline__ float fast_atan2(float y, float x) {
  float ax = fabsf(x), ay = fabsf(y);
  float mn = fminf(ax, ay), mx = fmaxf(ax, ay);
  float a = mn / (mx + 1e-30f);
  float s = a * a;
  float r = ((-0.0464964749f * s + 0.15931422f) * s - 0.327622764f) * s * a + a;
  if (ay > ax) r = 1.57079637f - r;
  if (x < 0.0f) r = 3.14159274f - r;
  return copysignf(r, y);
}

__device__ __forceinline__ unsigned packh2(float x, float y) {
  __half2 h = __floats2half2_rn(x, y);
  return *(unsigned*)&h;
}
__device__ __forceinline__ float2 unpackh2(unsigned u) {
  __half2 h = *(__half2*)&u;
  return __half22float2(h);
}

// ================= Cooperative single-pass kernel =================
__global__ __launch_bounds__(BT, 4) void wi_fused(
    const float* __restrict__ U, const float* __restrict__ x0,
    const float* __restrict__ dtp, DSum* __restrict__ bsum,
    float* __restrict__ out, int N)
{
  namespace cg = cooperative_groups;
  cg::grid_group grid = cg::this_grid();

  const int b = blockIdx.x;
  const int t = threadIdx.x;
  const int lane = t & 63, wid = t >> 6;
  const long Bb = (long)b * SPAN;

  __shared__ f32x4 stage[SEC_PAIRS];          // 32 KiB
  __shared__ double wsx[BT / 64], wsy[BT / 64];
  __shared__ float swx[BT / 64], swy[BT / 64];
  __shared__ double s_ox, s_oy, s_dtd;

  unsigned pk[PPT];                           // packed fp16 (uvx, uvy)
  float tsx = 0.f, tsy = 0.f;

  // ---- phase 1: read U once, tanh, keep uv in registers (fp16-packed) ----
  #pragma unroll
  for (int s = 0; s < SECS; ++s) {
    const long g0 = Bb + (long)s * SEC_PAIRS + (long)t * PPS;
    const f32x4* pbase = (const f32x4*)(U + 2 * g0);
    #pragma unroll
    for (int i = 0; i < PPS / 2; ++i) {
      const long p0 = g0 + 2 * i;
      f32x4 a;
      if (p0 + 2 <= (long)N) {
        a = pbase[i];
      } else {
        a.x = (p0 < (long)N)     ? U[2*p0]   : 0.f;
        a.y = (p0 < (long)N)     ? U[2*p0+1] : 0.f;
        a.z = (p0 + 1 < (long)N) ? U[2*p0+2] : 0.f;
        a.w = (p0 + 1 < (long)N) ? U[2*p0+3] : 0.f;
      }
      unsigned q0 = packh2(fast_tanh(a.x) * VMAX, fast_tanh(a.y) * VMAX);
      unsigned q1 = packh2(fast_tanh(a.z) * VMAX, fast_tanh(a.w) * VMAX);
      pk[s * PPS + 2 * i]     = q0;
      pk[s * PPS + 2 * i + 1] = q1;
      float2 r0 = unpackh2(q0), r1 = unpackh2(q1);  // sums of ROUNDED values
      tsx += r0.x + r1.x; tsy += r0.y + r1.y;
    }
  }
  {
    float rx = tsx, ry = tsy;
    #pragma unroll
    for (int o = 1; o < 64; o <<= 1) { rx += __shfl_xor(rx, o); ry += __shfl_xor(ry, o); }
    if (lane == 0) { wsx[wid] = (double)rx; wsy[wid] = (double)ry; }
    __syncthreads();
    if (t == 0) {
      double ax = 0.0, ay = 0.0;
      #pragma unroll
      for (int w = 0; w < BT / 64; ++w) { ax += wsx[w]; ay += wsy[w]; }
      bsum[b].x = ax; bsum[b].y = ay;     // uv units (no dt yet)
    }
  }
  __threadfence();
  grid.sync();

  // ---- phase 2: every block computes its exclusive prefix over bsum ----
  if (wid == 0) {
    double px = 0.0, py = 0.0;
    const int i0 = lane * (NB / 64);
    #pragma unroll
    for (int j = 0; j < NB / 64; ++j) {
      const int i = i0 + j;
      if (i < b) { px += bsum[i].x; py += bsum[i].y; }
    }
    #pragma unroll
    for (int o = 1; o < 64; o <<= 1) { px += __shfl_xor(px, o); py += __shfl_xor(py, o); }
    if (lane == 0) {
      const double dtd = (double)(*dtp);
      s_ox = (double)x0[0] + px * dtd;
      s_oy = (double)x0[1] + py * dtd;
      s_dtd = dtd;
    }
  }
  __syncthreads();
  const double ox = s_ox, oy = s_oy, dtd = s_dtd;

  // ---- phase 3: scan + emit (LDS stage + wave-contiguous nt stores) ----
  f32x4* o4 = (f32x4*)out;
  if (b == 0 && t == 0) {
    f32x4 r; r.x = x0[0]; r.y = x0[1]; r.z = x0[2]; r.w = x0[3];
    o4[0] = r;
  }
  float carx = 0.f, cary = 0.f;
  #pragma unroll
  for (int s = 0; s < SECS; ++s) {
    float ssx = 0.f, ssy = 0.f;
    #pragma unroll
    for (int k = 0; k < PPS; ++k) {
      float2 r = unpackh2(pk[s * PPS + k]);
      ssx += r.x; ssy += r.y;
    }
    float isx = ssx, isy = ssy;
    #pragma unroll
    for (int o = 1; o < 64; o <<= 1) {
      float ux = __shfl_up(isx, o), uy = __shfl_up(isy, o);
      if (lane >= o) { isx += ux; isy += uy; }
    }
    if (lane == 63) { swx[wid] = isx; swy[wid] = isy; }
    __syncthreads();
    float wox = 0.f, woy = 0.f, stx = 0.f, sty = 0.f;
    #pragma unroll
    for (int w = 0; w < BT / 64; ++w) {
      float a = swx[w], c = swy[w];
      if (w < wid) { wox += a; woy += c; }
      stx += a; sty += c;
    }
    float offx = carx + wox + (isx - ssx);
    float offy = cary + woy + (isy - ssy);
    carx += stx; cary += sty;
    #pragma unroll
    for (int k = 0; k < PPS; ++k) {
      float2 rr = unpackh2(pk[s * PPS + k]);
      offx += rr.x; offy += rr.y;
      float posx = (float)(ox + (double)offx * dtd);
      float posy = (float)(oy + (double)offy * dtd);
      float th = fast_atan2(rr.y, rr.x + 1e-9f);
      float vv = fminf(sqrtf(rr.x * rr.x + rr.y * rr.y + 1e-12f), VMAX);
      f32x4 r; r.x = posx; r.y = posy; r.z = th; r.w = vv;
      const int kk = t * PPS + k;
      stage[kk ^ ((kk >> 3) & 7)] = r;
    }
    __syncthreads();
    const long sb = Bb + (long)s * SEC_PAIRS;
    #pragma unroll
    for (int i = 0; i < PPS; ++i) {
      const int kk = i * BT + t;
      const long g = sb + kk;
      if (g < (long)N) __builtin_nontemporal_store(stage[kk ^ ((kk >> 3) & 7)], o4 + 1 + g);
    }
    __syncthreads();
  }
}

// ================= Fallback: proven R7 3-kernel path =================
__global__ __launch_bounds__(B1) void wi_partial(
    const float* __restrict__ U, const float* __restrict__ dtp,
    DSum* __restrict__ bsum, int N)
{
  const int t = threadIdx.x;
  const int lane = t & 63, wid = t >> 6;
  const long base = (long)blockIdx.x * CH1 + (long)t * IT1;
  float sx = 0.f, sy = 0.f;
  if (base + IT1 <= (long)N) {
    const f32x4* p = (const f32x4*)(U + 2 * base);
    #pragma unroll
    for (int i = 0; i < IT1 / 2; ++i) {
      f32x4 a = p[i];
      sx += fast_tanh(a.x) + fast_tanh(a.z);
      sy += fast_tanh(a.y) + fast_tanh(a.w);
    }
  } else {
    for (int i = 0; i < IT1; ++i) {
      long idx = base + i;
      if (idx < N) { sx += fast_tanh(U[2*idx]); sy += fast_tanh(U[2*idx+1]); }
    }
  }
  #pragma unroll
  for (int o = 1; o < 64; o <<= 1) { sx += __shfl_xor(sx, o); sy += __shfl_xor(sy, o); }
  __shared__ double wsx[B1/64], wsy[B1/64];
  if (lane == 0) { wsx[wid] = (double)sx; wsy[wid] = (double)sy; }
  __syncthreads();
  if (t == 0) {
    const float sc = VMAX * (*dtp);
    double ax = 0.0, ay = 0.0;
    #pragma unroll
    for (int w = 0; w < B1/64; ++w) { ax += wsx[w]; ay += wsy[w]; }
    bsum[blockIdx.x].x = ax * (double)sc;
    bsum[blockIdx.x].y = ay * (double)sc;
  }
}

__global__ __launch_bounds__(B2) void wi_scan_blocks(DSum* bsum, int nblocks)
{
  const int t = threadIdx.x;
  const int lane = t & 63, wid = t >> 6;
  const int per = (nblocks + B2 - 1) / B2;
  const int s = t * per;
  const int e = min(s + per, nblocks);
  double tx = 0.0, ty = 0.0;
  for (int i = s; i < e; ++i) { tx += bsum[i].x; ty += bsum[i].y; }
  double ix = tx, iy = ty;
  #pragma unroll
  for (int o = 1; o < 64; o <<= 1) {
    double ux = __shfl_up(ix, o), uy = __shfl_up(iy, o);
    if (lane >= o) { ix += ux; iy += uy; }
  }
  __shared__ double wx[B2/64], wy[B2/64];
  if (lane == 63) { wx[wid] = ix; wy[wid] = iy; }
  __syncthreads();
  double wbx = 0.0, wby = 0.0;
  #pragma unroll
  for (int w = 0; w < B2/64; ++w) {
    if (w < wid) { wbx += wx[w]; wby += wy[w]; }
  }
  double rx = wbx + ix - tx;
  double ry = wby + iy - ty;
  for (int i = s; i < e; ++i) {
    double vx = bsum[i].x, vy = bsum[i].y;
    bsum[i].x = rx; bsum[i].y = ry;
    rx += vx; ry += vy;
  }
}

__global__ __launch_bounds__(B1) void wi_emit(
    const float* __restrict__ U, const float* __restrict__ x0,
    const float* __restrict__ dtp, const DSum* __restrict__ boff,
    float* __restrict__ out, int N)
{
  __shared__ f32x4 stage[CH1];
  __shared__ float wsum_x[B1/64], wsum_y[B1/64];
  const int t = threadIdx.x;
  const int lane = t & 63, wid = t >> 6;
  const long base = (long)blockIdx.x * CH1 + (long)t * IT1;
  const float dt = *dtp;
  float vx[IT1], vy[IT1];
  const bool full = (base + IT1 <= (long)N);
  if (full) {
    const f32x4* p = (const f32x4*)(U + 2 * base);
    #pragma unroll
    for (int i = 0; i < IT1 / 2; ++i) {
      f32x4 a = p[i];
      vx[2*i]   = fast_tanh(a.x) * VMAX; vy[2*i]   = fast_tanh(a.y) * VMAX;
      vx[2*i+1] = fast_tanh(a.z) * VMAX; vy[2*i+1] = fast_tanh(a.w) * VMAX;
    }
  } else {
    for (int i = 0; i < IT1; ++i) {
      long idx = base + i;
      if (idx < N) { vx[i] = fast_tanh(U[2*idx]) * VMAX; vy[i] = fast_tanh(U[2*idx+1]) * VMAX; }
      else { vx[i] = 0.f; vy[i] = 0.f; }
    }
  }
  float px[IT1], py[IT1];
  float sx = 0.f, sy = 0.f;
  #pragma unroll
  for (int i = 0; i < IT1; ++i) { sx += vx[i]*dt; px[i] = sx; sy += vy[i]*dt; py[i] = sy; }
  const float totx = sx, toty = sy;
  #pragma unroll
  for (int o = 1; o < 64; o <<= 1) {
    float ux = __shfl_up(sx, o), uy = __shfl_up(sy, o);
    if (lane >= o) { sx += ux; sy += uy; }
  }
  if (lane == 63) { wsum_x[wid] = sx; wsum_y[wid] = sy; }
  __syncthreads();
  float wbx = 0.f, wby = 0.f;
  #pragma unroll
  for (int w = 0; w < B1/64; ++w) {
    if (w < wid) { wbx += wsum_x[w]; wby += wsum_y[w]; }
  }
  const float exb = wbx + sx - totx;
  const float eyb = wby + sy - toty;
  const double ox = boff[blockIdx.x].x + (double)x0[0];
  const double oy = boff[blockIdx.x].y + (double)x0[1];
  #pragma unroll
  for (int i = 0; i < IT1; ++i) {
    float posx = (float)(ox + (double)(exb + px[i]));
    float posy = (float)(oy + (double)(eyb + py[i]));
    float th = fast_atan2(vy[i], vx[i] + 1e-9f);
    float vv = fminf(sqrtf(vx[i]*vx[i] + vy[i]*vy[i] + 1e-12f), VMAX);
    f32x4 r; r.x = posx; r.y = posy; r.z = th; r.w = vv;
    const int k = t * IT1 + i;
    stage[k ^ ((k >> 3) & 7)] = r;
  }
  __syncthreads();
  const long tile0 = (long)blockIdx.x * CH1;
  f32x4* o4 = (f32x4*)out;
  #pragma unroll
  for (int i = 0; i < IT1; ++i) {
    const int k = i * B1 + t;
    const long g = tile0 + k;
    if (g < (long)N) __builtin_nontemporal_store(stage[k ^ ((k >> 3) & 7)], o4 + 1 + g);
  }
  if (blockIdx.x == 0 && t == 0) {
    f32x4 r; r.x = x0[0]; r.y = x0[1]; r.z = x0[2]; r.w = x0[3];
    o4[0] = r;
  }
}

extern "C" void kernel_launch(void* const* d_in, const int* in_sizes, int n_in,
                              void* d_out, int out_size, void* d_ws, size_t ws_size,
                              hipStream_t stream) {
  const float* x0 = (const float*)d_in[0];
  const float* U  = (const float*)d_in[1];
  const float* dt = (const float*)d_in[2];
  float* out = (float*)d_out;
  const int N = in_sizes[1] / 2;
  DSum* bsum = (DSum*)d_ws;

  // Gate the cooperative path on actual granted occupancy (deterministic).
  int maxPerCU = 0;
  hipError_t qerr = hipOccupancyMaxActiveBlocksPerMultiprocessor(&maxPerCU, wi_fused, BT, 0);
  int numCU = 0;
  hipDeviceProp_t props;
  if (hipGetDeviceProperties(&props, 0) == hipSuccess) numCU = props.multiProcessorCount;

  bool coop_ok = (qerr == hipSuccess) && (N <= NB * SPAN) &&
                 ((long)maxPerCU * numCU >= NB);
  if (coop_ok) {
    void* args[] = { (void*)&U, (void*)&x0, (void*)&dt, (void*)&bsum, (void*)&out, (void*)&N };
    hipError_t lerr = hipLaunchCooperativeKernel((void*)wi_fused, dim3(NB), dim3(BT),
                                                 args, 0, stream);
    if (lerr == hipSuccess) return;
  }

  const int nb = (N + CH1 - 1) / CH1;
  wi_partial<<<nb, B1, 0, stream>>>(U, dt, bsum, N);
  wi_scan_blocks<<<1, B2, 0, stream>>>(bsum, nb);
  wi_emit<<<nb, B1, 0, stream>>>(U, x0, dt, bsum, out, N);
}